// Round 1
// baseline (459.940 us; speedup 1.0000x reference)
//
#include <hip/hip_runtime.h>
#include <cstdint>
#include <cstddef>

// Problem constants
#define B_ 2
#define S_ 2048
#define D_ 2048
#define H_ 16
#define HD_ 128
#define NTOK 4096       // B_*S_
#define NQKV 6144       // 3*D_

typedef unsigned short u16;
typedef __attribute__((ext_vector_type(8))) __bf16 bf16x8;
typedef __attribute__((ext_vector_type(4))) float f32x4;

// fp32 -> bf16 (RNE), bit-level to avoid header API drift
__device__ __forceinline__ u16 f2bf(float f) {
  uint32_t u = __builtin_bit_cast(uint32_t, f);
  u = (u + 0x7FFFu + ((u >> 16) & 1u)) >> 16;
  return (u16)u;
}

__device__ __forceinline__ void gload_lds16(const void* g, void* l) {
  __builtin_amdgcn_global_load_lds(
      (const __attribute__((address_space(1))) void*)g,
      (__attribute__((address_space(3))) void*)l, 16, 0, 0);
}

// ---------------- conversion kernel ----------------
__global__ void cvt_f32_bf16(const float* __restrict__ src, u16* __restrict__ dst, int n8) {
  int idx = blockIdx.x * blockDim.x + threadIdx.x;
  int stride = gridDim.x * blockDim.x;
  for (int i = idx; i < n8; i += stride) {
    const float4* s = (const float4*)(src + (size_t)i * 8);
    float4 a = s[0], b = s[1];
    union { u16 u[8]; uint4 v; } o;
    o.u[0] = f2bf(a.x); o.u[1] = f2bf(a.y); o.u[2] = f2bf(a.z); o.u[3] = f2bf(a.w);
    o.u[4] = f2bf(b.x); o.u[5] = f2bf(b.y); o.u[6] = f2bf(b.z); o.u[7] = f2bf(b.w);
    *(uint4*)(dst + (size_t)i * 8) = o.v;
  }
}

// ---------------- shared GEMM main loop (m97 structure) ----------------
// C[m0..m0+127][n0..n0+127] += A[M][K] * B[N][K]^T   (both row-major, bf16)
// 256 threads = 4 waves in 2x2; each wave 64x64 via 4x4 frags of 16x16x32.
__device__ __forceinline__ void gemm_bt_tile(
    const u16* __restrict__ A, const u16* __restrict__ B,
    int lda, int ldb, int K, int m0, int n0,
    u16* As, u16* Bs, f32x4 acc[4][4])
{
  const int tid = threadIdx.x;
  const int lane = tid & 63;
  const int wid = tid >> 6;
  const int wr = wid >> 1, wc = wid & 1;
  const int fr = lane & 15, fq = lane >> 4;

  for (int k0 = 0; k0 < K; k0 += 32) {
    __syncthreads();   // previous compute done before overwriting LDS
    // stage A,B tiles: 128x32 bf16 each = 512 chunks of 16B; 256 thr * 2 iters
#pragma unroll
    for (int i = 0; i < 2; ++i) {
      int cbase = (i * 4 + wid) * 64;           // wave-uniform chunk base
      int c = cbase + lane;
      int r = c >> 2, c8 = (c & 3) * 8;
      gload_lds16(A + (size_t)(m0 + r) * lda + k0 + c8, As + (size_t)cbase * 8);
      gload_lds16(B + (size_t)(n0 + r) * ldb + k0 + c8, Bs + (size_t)cbase * 8);
    }
    __syncthreads();   // drains vmcnt(0): LDS data visible

    bf16x8 a[4], b[4];
#pragma unroll
    for (int m = 0; m < 4; ++m)
      a[m] = *(const bf16x8*)&As[(wr * 64 + m * 16 + fr) * 32 + fq * 8];
#pragma unroll
    for (int n = 0; n < 4; ++n)
      b[n] = *(const bf16x8*)&Bs[(wc * 64 + n * 16 + fr) * 32 + fq * 8];
#pragma unroll
    for (int m = 0; m < 4; ++m)
#pragma unroll
      for (int n = 0; n < 4; ++n)
        acc[m][n] = __builtin_amdgcn_mfma_f32_16x16x32_bf16(a[m], b[n], acc[m][n], 0, 0, 0);
  }
}

// ---------------- QKV projection GEMM ----------------
// C = hs @ Wqkv^T + b ; scatter epilogue into q,k (B,H,S,HD) and vT (B,H,HD,S)
__global__ __launch_bounds__(256) void qkv_gemm(
    const u16* __restrict__ hsb, const u16* __restrict__ wb,
    const float* __restrict__ bias,
    u16* __restrict__ qb, u16* __restrict__ kb, u16* __restrict__ vT)
{
  __shared__ alignas(16) u16 As[128 * 32];
  __shared__ alignas(16) u16 Bs[128 * 32];
  f32x4 acc[4][4];
  f32x4 z = {0.f, 0.f, 0.f, 0.f};
#pragma unroll
  for (int m = 0; m < 4; ++m)
#pragma unroll
    for (int n = 0; n < 4; ++n) acc[m][n] = z;

  int m0 = blockIdx.x * 128, n0 = blockIdx.y * 128;
  gemm_bt_tile(hsb, wb, D_, D_, D_, m0, n0, As, Bs, acc);

  const int lane = threadIdx.x & 63;
  const int wid = threadIdx.x >> 6;
  const int wr = wid >> 1, wc = wid & 1;
  const int fr = lane & 15, fq = lane >> 4;
#pragma unroll
  for (int m = 0; m < 4; ++m)
#pragma unroll
    for (int n = 0; n < 4; ++n) {
      int col = n0 + wc * 64 + n * 16 + fr;       // 0..6143
      float bv = bias[col];
      int t = col >> 11;                           // 0=q 1=k 2=v
      int d2 = col & 2047;
      int h = d2 >> 7, hd = d2 & 127;
#pragma unroll
      for (int r = 0; r < 4; ++r) {
        int row = m0 + wr * 64 + m * 16 + fq * 4 + r;   // 0..4095
        int bb = row >> 11, s = row & 2047;
        int bh = bb * H_ + h;
        u16 bf = f2bf(acc[m][n][r] + bv);
        if (t == 0)      qb[((size_t)bh * S_ + s) * HD_ + hd] = bf;
        else if (t == 1) kb[((size_t)bh * S_ + s) * HD_ + hd] = bf;
        else             vT[((size_t)bh * HD_ + hd) * S_ + s] = bf;
      }
    }
}

// ---------------- output projection GEMM ----------------
__global__ __launch_bounds__(256) void out_gemm(
    const u16* __restrict__ ctx, const u16* __restrict__ wo,
    const float* __restrict__ bias, float* __restrict__ out)
{
  __shared__ alignas(16) u16 As[128 * 32];
  __shared__ alignas(16) u16 Bs[128 * 32];
  f32x4 acc[4][4];
  f32x4 z = {0.f, 0.f, 0.f, 0.f};
#pragma unroll
  for (int m = 0; m < 4; ++m)
#pragma unroll
    for (int n = 0; n < 4; ++n) acc[m][n] = z;

  int m0 = blockIdx.x * 128, n0 = blockIdx.y * 128;
  gemm_bt_tile(ctx, wo, D_, D_, D_, m0, n0, As, Bs, acc);

  const int lane = threadIdx.x & 63;
  const int wid = threadIdx.x >> 6;
  const int wr = wid >> 1, wc = wid & 1;
  const int fr = lane & 15, fq = lane >> 4;
#pragma unroll
  for (int m = 0; m < 4; ++m)
#pragma unroll
    for (int n = 0; n < 4; ++n) {
      int col = n0 + wc * 64 + n * 16 + fr;
      float bv = bias[col];
#pragma unroll
      for (int r = 0; r < 4; ++r) {
        int row = m0 + wr * 64 + m * 16 + fq * 4 + r;
        out[(size_t)row * D_ + col] = acc[m][n][r] + bv;
      }
    }
}

// ---------------- flash attention ----------------
// grid: (S/64, B*H). 256 threads = 4 waves; wave handles 16 q-rows.
// K LDS [64][128] XOR-swizzled; V^T LDS [128][64] XOR-swizzled; P per-wave [16][64] swizzled.
__global__ __launch_bounds__(256) void attn(
    const u16* __restrict__ qb, const u16* __restrict__ kb,
    const u16* __restrict__ vT, u16* __restrict__ ctx)
{
  __shared__ alignas(16) u16 Kl[64 * 128];
  __shared__ alignas(16) u16 Vl[128 * 64];
  __shared__ alignas(16) u16 Pl[4][16 * 64];

  const int tid = threadIdx.x, lane = tid & 63, wid = tid >> 6;
  const int fr = lane & 15, fq = lane >> 4;
  const int bh = blockIdx.y;
  const int q0 = blockIdx.x * 64;
  const float scale = 0.08838834764831845f; // 1/sqrt(128)

  // Q fragments for this wave's 16 rows (once)
  const u16* qbase = qb + ((size_t)bh * S_ + q0 + wid * 16) * HD_;
  bf16x8 qa[4];
#pragma unroll
  for (int kc = 0; kc < 4; ++kc)
    qa[kc] = *(const bf16x8*)(qbase + (size_t)fr * HD_ + kc * 32 + fq * 8);

  f32x4 accv[8];
  f32x4 z = {0.f, 0.f, 0.f, 0.f};
#pragma unroll
  for (int n = 0; n < 8; ++n) accv[n] = z;
  float m_run[4], l_run[4];
#pragma unroll
  for (int r = 0; r < 4; ++r) { m_run[r] = -1e30f; l_run[r] = 0.f; }

  const u16* Kg = kb + (size_t)bh * S_ * HD_;
  const u16* Vg = vT + (size_t)bh * HD_ * S_;

  for (int kv = 0; kv < S_; kv += 64) {
    __syncthreads();
    // stage K [64][128] and V^T [128][64], swizzled (reg-staged ds_write_b128)
#pragma unroll
    for (int i = 0; i < 4; ++i) {
      int c = i * 256 + tid;
      {
        int row = c >> 4, cc = c & 15;
        uint4 t4 = *(const uint4*)(Kg + (size_t)(kv + row) * HD_ + cc * 8);
        int off = row * 128 + ((cc * 8) ^ ((row & 7) << 3));
        *(uint4*)&Kl[off] = t4;
      }
      {
        int rv = c >> 3, cv = c & 7;
        uint4 v4 = *(const uint4*)(Vg + (size_t)rv * S_ + kv + cv * 8);
        int offv = rv * 64 + ((cv * 8) ^ ((rv & 7) << 3));
        *(uint4*)&Vl[offv] = v4;
      }
    }
    __syncthreads();

    // QK^T: sc[j] = S[16q x 16k] for k block j
    f32x4 sc[4];
#pragma unroll
    for (int j = 0; j < 4; ++j) {
      sc[j] = z;
#pragma unroll
      for (int kc = 0; kc < 4; ++kc) {
        int row = j * 16 + fr;
        int off = row * 128 + ((fq * 8 + kc * 32) ^ ((row & 7) << 3));
        bf16x8 kf = *(const bf16x8*)&Kl[off];
        sc[j] = __builtin_amdgcn_mfma_f32_16x16x32_bf16(qa[kc], kf, sc[j], 0, 0, 0);
      }
    }

    // online softmax (per q row = fq*4+r, replicated over the 16-lane group)
    float mloc[4];
#pragma unroll
    for (int r = 0; r < 4; ++r) {
      float mx = -1e30f;
#pragma unroll
      for (int j = 0; j < 4; ++j) { sc[j][r] *= scale; mx = fmaxf(mx, sc[j][r]); }
      mloc[r] = mx;
    }
#pragma unroll
    for (int mask = 1; mask < 16; mask <<= 1)
#pragma unroll
      for (int r = 0; r < 4; ++r)
        mloc[r] = fmaxf(mloc[r], __shfl_xor(mloc[r], mask));

    float corr[4], rs[4];
#pragma unroll
    for (int r = 0; r < 4; ++r) {
      float mn = fmaxf(m_run[r], mloc[r]);
      corr[r] = __expf(m_run[r] - mn);
      m_run[r] = mn;
      float ssum = 0.f;
#pragma unroll
      for (int j = 0; j < 4; ++j) {
        float p = __expf(sc[j][r] - mn);
        sc[j][r] = p;
        ssum += p;
      }
      rs[r] = ssum;
    }
#pragma unroll
    for (int mask = 1; mask < 16; mask <<= 1)
#pragma unroll
      for (int r = 0; r < 4; ++r)
        rs[r] += __shfl_xor(rs[r], mask);
#pragma unroll
    for (int r = 0; r < 4; ++r) l_run[r] = l_run[r] * corr[r] + rs[r];
#pragma unroll
    for (int n = 0; n < 8; ++n)
#pragma unroll
      for (int r = 0; r < 4; ++r) accv[n][r] *= corr[r];

    // P -> LDS (wave-private, swizzled): lane holds P[q=fq*4+r][k=j*16+fr]
    u16* Pw = Pl[wid];
#pragma unroll
    for (int j = 0; j < 4; ++j)
#pragma unroll
      for (int r = 0; r < 4; ++r) {
        int q = fq * 4 + r, k = j * 16 + fr;
        Pw[q * 64 + (k ^ ((q & 7) << 3))] = f2bf(sc[j][r]);
      }

    // PV: acc[16q x 128d] += P[16q x 64k] * V[64k x 128d]  (B-frags from V^T rows)
#pragma unroll
    for (int kc = 0; kc < 2; ++kc) {
      int koff = (kc * 32 + fq * 8) ^ ((fr & 7) << 3);
      bf16x8 pa = *(const bf16x8*)&Pl[wid][fr * 64 + koff];
#pragma unroll
      for (int n = 0; n < 8; ++n) {
        int row = n * 16 + fr;
        int off = row * 64 + ((fq * 8 + kc * 32) ^ ((row & 7) << 3));
        bf16x8 vf = *(const bf16x8*)&Vl[off];
        accv[n] = __builtin_amdgcn_mfma_f32_16x16x32_bf16(pa, vf, accv[n], 0, 0, 0);
      }
    }
  }

  // epilogue: ctx (B,S,D) bf16, D col = h*128 + d
  u16* cbase = ctx + (((size_t)(bh >> 4)) * S_ + q0 + wid * 16) * D_ + (size_t)(bh & 15) * HD_;
#pragma unroll
  for (int n = 0; n < 8; ++n)
#pragma unroll
    for (int r = 0; r < 4; ++r) {
      int q = fq * 4 + r;
      cbase[(size_t)q * D_ + n * 16 + fr] = f2bf(accv[n][r] / l_run[r]);
    }
}

// ---------------- launcher ----------------
extern "C" void kernel_launch(void* const* d_in, const int* in_sizes, int n_in,
                              void* d_out, int out_size, void* d_ws, size_t ws_size,
                              hipStream_t stream) {
  const float* hs   = (const float*)d_in[0];
  const float* wqkv = (const float*)d_in[1];
  const float* bqkv = (const float*)d_in[2];
  const float* wo   = (const float*)d_in[3];
  const float* bo   = (const float*)d_in[4];
  float* out = (float*)d_out;

  char* ws = (char*)d_ws;
  u16* hsb   = (u16*)(ws);                      // 16.0 MiB  (4096*2048)
  u16* wqkvb = (u16*)(ws + 16777216);           // 24.0 MiB  (6144*2048)
  u16* wob   = (u16*)(ws + 41943040);           //  8.0 MiB  (2048*2048)
  u16* qb    = (u16*)(ws + 50331648);           // 16.0 MiB  (B,H,S,HD)
  u16* kb    = (u16*)(ws + 67108864);           // 16.0 MiB
  u16* vT    = (u16*)(ws + 83886080);           // 16.0 MiB  (B,H,HD,S)
  u16* ctx   = (u16*)(ws + 100663296);          // 16.0 MiB  (B,S,D)

  cvt_f32_bf16<<<2048, 256, 0, stream>>>(hs,   hsb,   (B_ * S_ * D_) / 8);
  cvt_f32_bf16<<<2048, 256, 0, stream>>>(wqkv, wqkvb, (NQKV * D_) / 8);
  cvt_f32_bf16<<<1024, 256, 0, stream>>>(wo,   wob,   (D_ * D_) / 8);

  qkv_gemm<<<dim3(NTOK / 128, NQKV / 128), 256, 0, stream>>>(hsb, wqkvb, bqkv, qb, kb, vT);
  attn<<<dim3(S_ / 64, B_ * H_), 256, 0, stream>>>(qb, kb, vT, ctx);
  out_gemm<<<dim3(NTOK / 128, D_ / 128), 256, 0, stream>>>(ctx, wob, bo, out);
}

// Round 2
// 308.602 us; speedup vs baseline: 1.4904x; 1.4904x over previous
//
#include <hip/hip_runtime.h>
#include <cstdint>
#include <cstddef>

// Problem constants
#define B_ 2
#define S_ 2048
#define D_ 2048
#define H_ 16
#define HD_ 128
#define NTOK 4096       // B_*S_
#define NQKV 6144       // 3*D_

typedef unsigned short u16;
typedef __attribute__((ext_vector_type(8))) __bf16 bf16x8;
typedef __attribute__((ext_vector_type(4))) float f32x4;

// fp32 -> bf16 (RNE), bit-level to avoid header API drift
__device__ __forceinline__ u16 f2bf(float f) {
  uint32_t u = __builtin_bit_cast(uint32_t, f);
  u = (u + 0x7FFFu + ((u >> 16) & 1u)) >> 16;
  return (u16)u;
}

__device__ __forceinline__ void gload_lds16(const void* g, void* l) {
  __builtin_amdgcn_global_load_lds(
      (const __attribute__((address_space(1))) void*)g,
      (__attribute__((address_space(3))) void*)l, 16, 0, 0);
}

// ---------------- conversion kernel ----------------
__global__ void cvt_f32_bf16(const float* __restrict__ src, u16* __restrict__ dst, int n8) {
  int idx = blockIdx.x * blockDim.x + threadIdx.x;
  int stride = gridDim.x * blockDim.x;
  for (int i = idx; i < n8; i += stride) {
    const float4* s = (const float4*)(src + (size_t)i * 8);
    float4 a = s[0], b = s[1];
    union { u16 u[8]; uint4 v; } o;
    o.u[0] = f2bf(a.x); o.u[1] = f2bf(a.y); o.u[2] = f2bf(a.z); o.u[3] = f2bf(a.w);
    o.u[4] = f2bf(b.x); o.u[5] = f2bf(b.y); o.u[6] = f2bf(b.z); o.u[7] = f2bf(b.w);
    *(uint4*)(dst + (size_t)i * 8) = o.v;
  }
}

// ---------------- shared GEMM main loop (m97 structure) ----------------
// C[m0..m0+127][n0..n0+127] += A[M][K] * B[N][K]^T   (both row-major, bf16)
// 256 threads = 4 waves in 2x2; each wave 64x64 via 4x4 frags of 16x16x32.
__device__ __forceinline__ void gemm_bt_tile(
    const u16* __restrict__ A, const u16* __restrict__ B,
    int lda, int ldb, int K, int m0, int n0,
    u16* As, u16* Bs, f32x4 acc[4][4])
{
  const int tid = threadIdx.x;
  const int lane = tid & 63;
  const int wid = tid >> 6;
  const int wr = wid >> 1, wc = wid & 1;
  const int fr = lane & 15, fq = lane >> 4;

  for (int k0 = 0; k0 < K; k0 += 32) {
    __syncthreads();   // previous compute done before overwriting LDS
#pragma unroll
    for (int i = 0; i < 2; ++i) {
      int cbase = (i * 4 + wid) * 64;           // wave-uniform chunk base
      int c = cbase + lane;
      int r = c >> 2, c8 = (c & 3) * 8;
      gload_lds16(A + (size_t)(m0 + r) * lda + k0 + c8, As + (size_t)cbase * 8);
      gload_lds16(B + (size_t)(n0 + r) * ldb + k0 + c8, Bs + (size_t)cbase * 8);
    }
    __syncthreads();   // drains vmcnt(0): LDS data visible

    bf16x8 a[4], b[4];
#pragma unroll
    for (int m = 0; m < 4; ++m)
      a[m] = *(const bf16x8*)&As[(wr * 64 + m * 16 + fr) * 32 + fq * 8];
#pragma unroll
    for (int n = 0; n < 4; ++n)
      b[n] = *(const bf16x8*)&Bs[(wc * 64 + n * 16 + fr) * 32 + fq * 8];
#pragma unroll
    for (int m = 0; m < 4; ++m)
#pragma unroll
      for (int n = 0; n < 4; ++n)
        acc[m][n] = __builtin_amdgcn_mfma_f32_16x16x32_bf16(a[m], b[n], acc[m][n], 0, 0, 0);
  }
}

// ---------------- QKV projection GEMM ----------------
// C = hs @ Wqkv^T + b ; scatter epilogue into q,k (B,H,S,HD) and vT (B,H,HD,S)
// q is pre-scaled by 1/sqrt(HD) here (free; removes per-tile muls in attn).
__global__ __launch_bounds__(256) void qkv_gemm(
    const u16* __restrict__ hsb, const u16* __restrict__ wb,
    const float* __restrict__ bias,
    u16* __restrict__ qb, u16* __restrict__ kb, u16* __restrict__ vT)
{
  __shared__ alignas(16) u16 As[128 * 32];
  __shared__ alignas(16) u16 Bs[128 * 32];
  f32x4 acc[4][4];
  f32x4 z = {0.f, 0.f, 0.f, 0.f};
#pragma unroll
  for (int m = 0; m < 4; ++m)
#pragma unroll
    for (int n = 0; n < 4; ++n) acc[m][n] = z;

  int m0 = blockIdx.x * 128, n0 = blockIdx.y * 128;
  gemm_bt_tile(hsb, wb, D_, D_, D_, m0, n0, As, Bs, acc);

  const float qscale = 0.08838834764831845f; // 1/sqrt(128)
  const int lane = threadIdx.x & 63;
  const int wid = threadIdx.x >> 6;
  const int wr = wid >> 1, wc = wid & 1;
  const int fr = lane & 15, fq = lane >> 4;
#pragma unroll
  for (int m = 0; m < 4; ++m)
#pragma unroll
    for (int n = 0; n < 4; ++n) {
      int col = n0 + wc * 64 + n * 16 + fr;       // 0..6143
      float bv = bias[col];
      int t = col >> 11;                           // 0=q 1=k 2=v
      int d2 = col & 2047;
      int h = d2 >> 7, hd = d2 & 127;
#pragma unroll
      for (int r = 0; r < 4; ++r) {
        int row = m0 + wr * 64 + m * 16 + fq * 4 + r;   // 0..4095
        int bb = row >> 11, s = row & 2047;
        int bh = bb * H_ + h;
        float val = acc[m][n][r] + bv;
        if (t == 0)      qb[((size_t)bh * S_ + s) * HD_ + hd] = f2bf(val * qscale);
        else if (t == 1) kb[((size_t)bh * S_ + s) * HD_ + hd] = f2bf(val);
        else             vT[((size_t)bh * HD_ + hd) * S_ + s] = f2bf(val);
      }
    }
}

// ---------------- output projection GEMM ----------------
__global__ __launch_bounds__(256) void out_gemm(
    const u16* __restrict__ ctx, const u16* __restrict__ wo,
    const float* __restrict__ bias, float* __restrict__ out)
{
  __shared__ alignas(16) u16 As[128 * 32];
  __shared__ alignas(16) u16 Bs[128 * 32];
  f32x4 acc[4][4];
  f32x4 z = {0.f, 0.f, 0.f, 0.f};
#pragma unroll
  for (int m = 0; m < 4; ++m)
#pragma unroll
    for (int n = 0; n < 4; ++n) acc[m][n] = z;

  int m0 = blockIdx.x * 128, n0 = blockIdx.y * 128;
  gemm_bt_tile(ctx, wo, D_, D_, D_, m0, n0, As, Bs, acc);

  const int lane = threadIdx.x & 63;
  const int wid = threadIdx.x >> 6;
  const int wr = wid >> 1, wc = wid & 1;
  const int fr = lane & 15, fq = lane >> 4;
#pragma unroll
  for (int m = 0; m < 4; ++m)
#pragma unroll
    for (int n = 0; n < 4; ++n) {
      int col = n0 + wc * 64 + n * 16 + fr;
      float bv = bias[col];
#pragma unroll
      for (int r = 0; r < 4; ++r) {
        int row = m0 + wr * 64 + m * 16 + fq * 4 + r;
        out[(size_t)row * D_ + col] = acc[m][n][r] + bv;
      }
    }
}

// ---------------- flash attention v2 ----------------
// grid: (S/128, B*H). 256 threads = 4 waves; wave owns 32 q-rows.
// Swapped QK^T (mfma(K,Q) -> S^T): softmax stats live at q = lane&15 ("col-space"),
// accumulator rows at q = fq*4+r ("row-space"); bpermute bridges only on rescale.
// Defer-max (THR=8) skips rescale after tile 0 on this data.
__global__ __launch_bounds__(256, 2) void attn(
    const u16* __restrict__ qb, const u16* __restrict__ kb,
    const u16* __restrict__ vT, u16* __restrict__ ctx)
{
  __shared__ alignas(16) u16 Kl[64 * 128];
  __shared__ alignas(16) u16 Vl[128 * 64];
  __shared__ alignas(16) u16 Pl[4][32 * 64];

  const int tid = threadIdx.x, lane = tid & 63, wid = tid >> 6;
  const int fr = lane & 15, fq = lane >> 4;
  const int bh = blockIdx.y;
  const int q0 = blockIdx.x * 128 + wid * 32;
  f32x4 z = {0.f, 0.f, 0.f, 0.f};

  // Q fragments (B-operand layout): qa[h][kc] = Q[q0+h*16+fr][kc*32+fq*8 ..+8]
  const u16* qbase = qb + ((size_t)bh * S_ + q0) * HD_;
  bf16x8 qa[2][4];
#pragma unroll
  for (int h = 0; h < 2; ++h)
#pragma unroll
    for (int kc = 0; kc < 4; ++kc)
      qa[h][kc] = *(const bf16x8*)(qbase + (size_t)(h * 16 + fr) * HD_ + kc * 32 + fq * 8);

  f32x4 accv[2][8];
#pragma unroll
  for (int h = 0; h < 2; ++h)
#pragma unroll
    for (int n = 0; n < 8; ++n) accv[h][n] = z;
  float m_run[2] = {-1e30f, -1e30f};
  float l_run[2] = {0.f, 0.f};

  const u16* Kg = kb + (size_t)bh * S_ * HD_;
  const u16* Vg = vT + (size_t)bh * HD_ * S_;

  for (int kv = 0; kv < S_; kv += 64) {
    __syncthreads();
    // stage K [64][128] and V^T [128][64], XOR-swizzled (reg-staged)
#pragma unroll
    for (int i = 0; i < 4; ++i) {
      int c = i * 256 + tid;
      {
        int row = c >> 4, cc = c & 15;
        uint4 t4 = *(const uint4*)(Kg + (size_t)(kv + row) * HD_ + cc * 8);
        *(uint4*)&Kl[row * 128 + ((cc * 8) ^ ((row & 7) << 3))] = t4;
      }
      {
        int rv = c >> 3, cv = c & 7;
        uint4 v4 = *(const uint4*)(Vg + (size_t)rv * S_ + kv + cv * 8);
        *(uint4*)&Vl[rv * 64 + ((cv * 8) ^ ((rv & 7) << 3))] = v4;
      }
    }
    __syncthreads();

    // QK^T swapped: sc[h][j][r] = S[k = j*16+fq*4+r][q = fr+16h] (pre-scaled q)
    f32x4 sc[2][4];
#pragma unroll
    for (int j = 0; j < 4; ++j) {
      f32x4 s0 = z, s1 = z;
#pragma unroll
      for (int kc = 0; kc < 4; ++kc) {
        int row = j * 16 + fr;
        bf16x8 kf = *(const bf16x8*)&Kl[row * 128 + ((kc * 32 + fq * 8) ^ ((row & 7) << 3))];
        s0 = __builtin_amdgcn_mfma_f32_16x16x32_bf16(kf, qa[0][kc], s0, 0, 0, 0);
        s1 = __builtin_amdgcn_mfma_f32_16x16x32_bf16(kf, qa[1][kc], s1, 0, 0, 0);
      }
      sc[0][j] = s0; sc[1][j] = s1;
    }

    // per-lane max over 16 k-values, reduce across fq groups (masks 16,32)
    float pmax[2];
#pragma unroll
    for (int h = 0; h < 2; ++h) {
      float mx = sc[h][0][0];
#pragma unroll
      for (int j = 0; j < 4; ++j)
#pragma unroll
        for (int r = 0; r < 4; ++r) mx = fmaxf(mx, sc[h][j][r]);
      mx = fmaxf(mx, __shfl_xor(mx, 16));
      mx = fmaxf(mx, __shfl_xor(mx, 32));
      pmax[h] = mx;
    }

    // defer-max: rescale only if some row grew past THR=8
    int need = (pmax[0] > m_run[0] + 8.f) || (pmax[1] > m_run[1] + 8.f);
    if (__any(need)) {
#pragma unroll
      for (int h = 0; h < 2; ++h) {
        float mn = fmaxf(m_run[h], pmax[h]);
        float corr = __expf(m_run[h] - mn);
        m_run[h] = mn;
        l_run[h] *= corr;
        // redistribute corr from col-space (q=fr) to row-space (q=fq*4+r)
#pragma unroll
        for (int r = 0; r < 4; ++r) {
          float rc = __shfl(corr, (lane & 48) | (fq * 4 + r));
#pragma unroll
          for (int n = 0; n < 8; ++n) accv[h][n][r] *= rc;
        }
      }
    }

    // P = exp(S - m), row sums (col-space), pack to LDS (swizzled, b64)
    u16* Pw = Pl[wid];
#pragma unroll
    for (int h = 0; h < 2; ++h) {
      float ls = 0.f;
#pragma unroll
      for (int j = 0; j < 4; ++j) {
        union { u16 u[4]; ushort4 v; } pk;
#pragma unroll
        for (int r = 0; r < 4; ++r) {
          float p = __expf(sc[h][j][r] - m_run[h]);
          ls += p;
          pk.u[r] = f2bf(p);
        }
        int prow = h * 16 + fr;
        *(ushort4*)&Pw[prow * 64 + ((j * 16 + fq * 4) ^ ((fr & 7) << 3))] = pk.v;
      }
      ls += __shfl_xor(ls, 16);
      ls += __shfl_xor(ls, 32);
      l_run[h] += ls;
    }

    // PV: accv[h][n] += P[h-tile 16q x 64k] * V[64k x 128d]
#pragma unroll
    for (int kc = 0; kc < 2; ++kc) {
      int pcol = (kc * 32 + fq * 8) ^ ((fr & 7) << 3);
      bf16x8 pa0 = *(const bf16x8*)&Pw[fr * 64 + pcol];
      bf16x8 pa1 = *(const bf16x8*)&Pw[(16 + fr) * 64 + pcol];
#pragma unroll
      for (int n = 0; n < 8; ++n) {
        int row = n * 16 + fr;
        bf16x8 vf = *(const bf16x8*)&Vl[row * 64 + ((kc * 32 + fq * 8) ^ ((row & 7) << 3))];
        accv[0][n] = __builtin_amdgcn_mfma_f32_16x16x32_bf16(pa0, vf, accv[0][n], 0, 0, 0);
        accv[1][n] = __builtin_amdgcn_mfma_f32_16x16x32_bf16(pa1, vf, accv[1][n], 0, 0, 0);
      }
    }
  }

  // epilogue: bring l into row-space once, divide, store ctx (B,S,D)
  float inv[2][4];
#pragma unroll
  for (int h = 0; h < 2; ++h)
#pragma unroll
    for (int r = 0; r < 4; ++r) {
      float l = __shfl(l_run[h], (lane & 48) | (fq * 4 + r));
      inv[h][r] = 1.f / l;
    }
  u16* cb = ctx + (((size_t)(bh >> 4)) * S_ + blockIdx.x * 128 + wid * 32) * D_ + (size_t)(bh & 15) * HD_;
#pragma unroll
  for (int h = 0; h < 2; ++h)
#pragma unroll
    for (int n = 0; n < 8; ++n)
#pragma unroll
      for (int r = 0; r < 4; ++r) {
        int q = h * 16 + fq * 4 + r;
        cb[(size_t)q * D_ + n * 16 + fr] = f2bf(accv[h][n][r] * inv[h][r]);
      }
}

// ---------------- launcher ----------------
extern "C" void kernel_launch(void* const* d_in, const int* in_sizes, int n_in,
                              void* d_out, int out_size, void* d_ws, size_t ws_size,
                              hipStream_t stream) {
  const float* hs   = (const float*)d_in[0];
  const float* wqkv = (const float*)d_in[1];
  const float* bqkv = (const float*)d_in[2];
  const float* wo   = (const float*)d_in[3];
  const float* bo   = (const float*)d_in[4];
  float* out = (float*)d_out;

  char* ws = (char*)d_ws;
  u16* hsb   = (u16*)(ws);                      // 16.0 MiB  (4096*2048)
  u16* wqkvb = (u16*)(ws + 16777216);           // 24.0 MiB  (6144*2048)
  u16* wob   = (u16*)(ws + 41943040);           //  8.0 MiB  (2048*2048)
  u16* qb    = (u16*)(ws + 50331648);           // 16.0 MiB  (B,H,S,HD) pre-scaled
  u16* kb    = (u16*)(ws + 67108864);           // 16.0 MiB
  u16* vT    = (u16*)(ws + 83886080);           // 16.0 MiB  (B,H,HD,S)
  u16* ctx   = (u16*)(ws + 100663296);          // 16.0 MiB  (B,S,D)

  cvt_f32_bf16<<<2048, 256, 0, stream>>>(hs,   hsb,   (B_ * S_ * D_) / 8);
  cvt_f32_bf16<<<2048, 256, 0, stream>>>(wqkv, wqkvb, (NQKV * D_) / 8);
  cvt_f32_bf16<<<1024, 256, 0, stream>>>(wo,   wob,   (D_ * D_) / 8);

  qkv_gemm<<<dim3(NTOK / 128, NQKV / 128), 256, 0, stream>>>(hsb, wqkvb, bqkv, qb, kb, vT);
  attn<<<dim3(S_ / 128, B_ * H_), 256, 0, stream>>>(qb, kb, vT, ctx);
  out_gemm<<<dim3(NTOK / 128, D_ / 128), 256, 0, stream>>>(ctx, wob, bo, out);
}